// Round 8
// baseline (3255.862 us; speedup 1.0000x reference)
//
#include <hip/hip_runtime.h>
#include <math.h>

// ---- problem constants (match reference) ----
#define D     1024
#define NH    8
#define DHD   128
#define NL    12
#define NE    4
#define FF    2048
#define NCLS  10
#define BB    4
#define SS    512
#define TT    (BB*SS)          // 2048 tokens
#define EPSV  1e-5f
#define SPARS 0.5f

typedef __attribute__((ext_vector_type(8))) short bf16x8;
typedef __attribute__((ext_vector_type(4))) float f32x4;
typedef unsigned short ushortT;

__device__ __forceinline__ ushortT f2bf(float f) {
    unsigned u = __float_as_uint(f);
    u += 0x7FFF + ((u >> 16) & 1);      // RNE
    return (ushortT)(u >> 16);
}
__device__ __forceinline__ float bf2f(ushortT h) {
    return __uint_as_float(((unsigned)h) << 16);
}

// =====================================================================
// MFMA GEMM: C[M,N] = act(A[M,K] @ Bw[N,K]^T + bias[N])
// A bf16 [*][Ktot]; Bw fp32 (bf16 convert at staging). 128xBN tile,
// BK=32.  BN=128: 4 waves 2x2, 4x4 frags.  BN=64: 4 waves 4x1 (32-row
// slabs), 2x4 frags — doubles block count for grid-starved GEMMs.
// MODE: 0 = bf16 out, 1 = f32 out.  ACT: 1 = exact GELU.
// SK>1 : blockIdx.z = K-chunk; f32 partials at Cv + z*M*N, no bias/act.
// EPI 0: standard.  EPI 2: gathered-A expert GEMM (slotTok rows, cnt
// early-exit; output rows are slots).
// =====================================================================
#define LDP 40   // LDS row pitch in bf16 elems (32 data + 8 pad)

template<int MODE, int SK, int ACT, int BN, int EPI>
__global__ __launch_bounds__(256)
void gemm_mfma(const ushortT* __restrict__ A, const float* __restrict__ Bw,
               const float* __restrict__ bias, void* __restrict__ Cv,
               int M, int N, int Ktot, int Klen, long eBw, long eBias, long eC,
               const int* __restrict__ slotTok, const int* __restrict__ cnt)
{
    const int z = blockIdx.z;
    const int m0 = blockIdx.y * 128;
    const int n0 = blockIdx.x * BN;

    int cntE = 0;
    if constexpr (EPI == 2) {
        cntE = cnt[z];
        if (m0 >= cntE) return;      // block-uniform early exit
    }

    int koff = 0;
    float* Cf = nullptr; ushortT* Ch = nullptr;
    if constexpr (SK > 1) {
        koff = z * Klen;
        Cf = (float*)Cv + (size_t)z * M * N;
    } else {
        Bw   += (size_t)z * eBw;
        bias += (size_t)z * eBias;
        if constexpr (MODE == 0) Ch = (ushortT*)Cv + (size_t)z * eC;
        else                     Cf = (float*)Cv   + (size_t)z * eC;
    }

    constexpr int MR = (BN == 128) ? 4 : 2;
    __shared__ ushortT Asl[128 * LDP];
    __shared__ ushortT Bsl[BN * LDP];

    const int tid  = threadIdx.x;
    const int wave = tid >> 6, lane = tid & 63;
    const int wm = (BN == 128) ? (wave >> 1) * 64 : wave * 32;
    const int wn = (BN == 128) ? (wave & 1) * 64 : 0;
    const int fr = lane & 15;
    const int fq = lane >> 4;

    // A staging: 128 rows x 32 k bf16; 2x bf16x8 per thread
    const int arow = tid >> 1;
    const int akc  = (tid & 1) * 2;
    const ushortT* Ag;
    if constexpr (EPI == 2) {
        const int rsl = m0 + arow;
        const int tok = (rsl < cntE) ? slotTok[(size_t)z*TT + rsl] : 0;
        Ag = A + (size_t)tok * Ktot;
    } else {
        Ag = A + (size_t)(m0 + arow) * Ktot + koff;
    }
    // B staging: fp32 -> bf16
    const int srow = (BN == 128) ? (tid >> 3) : (tid >> 2);
    const int scb  = (BN == 128) ? (tid & 7) : (tid & 3);
    const float* Bg = Bw + (size_t)(n0 + srow) * Ktot + koff + scb * 4;

    f32x4 acc[MR][4] = {};

    for (int k0 = 0; k0 < Klen; k0 += 32) {
        bf16x8 av8[2];
        float4 bv[4];
        #pragma unroll
        for (int u = 0; u < 2; ++u)
            av8[u] = *reinterpret_cast<const bf16x8*>(Ag + k0 + (akc + u) * 8);
        if constexpr (BN == 128) {
            #pragma unroll
            for (int p = 0; p < 4; ++p)
                bv[p] = *reinterpret_cast<const float4*>(Bg + (size_t)(32*p) * Ktot + k0);
        } else {
            bv[0] = *reinterpret_cast<const float4*>(Bg + k0);
            bv[1] = *reinterpret_cast<const float4*>(Bg + k0 + 16);
        }
        __syncthreads();
        #pragma unroll
        for (int u = 0; u < 2; ++u)
            *reinterpret_cast<bf16x8*>(&Asl[arow*LDP + (akc + u)*8]) = av8[u];
        if constexpr (BN == 128) {
            #pragma unroll
            for (int p = 0; p < 4; ++p) {
                ushort4 b4; b4.x=f2bf(bv[p].x); b4.y=f2bf(bv[p].y); b4.z=f2bf(bv[p].z); b4.w=f2bf(bv[p].w);
                *reinterpret_cast<ushort4*>(&Bsl[(srow + 32*p)*LDP + scb*4]) = b4;
            }
        } else {
            ushort4 b0; b0.x=f2bf(bv[0].x); b0.y=f2bf(bv[0].y); b0.z=f2bf(bv[0].z); b0.w=f2bf(bv[0].w);
            ushort4 b1; b1.x=f2bf(bv[1].x); b1.y=f2bf(bv[1].y); b1.z=f2bf(bv[1].z); b1.w=f2bf(bv[1].w);
            *reinterpret_cast<ushort4*>(&Bsl[srow*LDP + scb*4])      = b0;
            *reinterpret_cast<ushort4*>(&Bsl[srow*LDP + scb*4 + 16]) = b1;
        }
        __syncthreads();

        bf16x8 af[MR], bfr[4];
        #pragma unroll
        for (int i = 0; i < MR; ++i)
            af[i]  = *reinterpret_cast<const bf16x8*>(&Asl[(wm + i*16 + fr)*LDP + fq*8]);
        #pragma unroll
        for (int j = 0; j < 4; ++j)
            bfr[j] = *reinterpret_cast<const bf16x8*>(&Bsl[(wn + j*16 + fr)*LDP + fq*8]);
        #pragma unroll
        for (int i = 0; i < MR; ++i)
            #pragma unroll
            for (int j = 0; j < 4; ++j)
                acc[i][j] = __builtin_amdgcn_mfma_f32_16x16x32_bf16(af[i], bfr[j], acc[i][j], 0, 0, 0);
    }

    #pragma unroll
    for (int j = 0; j < 4; ++j) {
        const int n = n0 + wn + j*16 + fr;
        float bb = 0.f;
        if constexpr (SK == 1) bb = bias[n];
        #pragma unroll
        for (int i = 0; i < MR; ++i) {
            const int mb = m0 + wm + i*16 + fq*4;
            if constexpr (SK > 1) {
                #pragma unroll
                for (int r = 0; r < 4; ++r)
                    Cf[(size_t)(mb + r) * N + n] = acc[i][j][r];
            } else if constexpr (MODE == 0) {
                #pragma unroll
                for (int r = 0; r < 4; ++r) {
                    float u = acc[i][j][r] + bb;
                    if constexpr (ACT == 1) u = 0.5f*u*(1.0f + erff(u*0.70710678118654752f));
                    Ch[(size_t)(mb + r) * N + n] = f2bf(u);
                }
            } else {
                #pragma unroll
                for (int r = 0; r < 4; ++r) {
                    float u = acc[i][j][r] + bb;
                    if constexpr (ACT == 1) u = 0.5f*u*(1.0f + erff(u*0.70710678118654752f));
                    Cf[(size_t)(mb + r) * N + n] = u;
                }
            }
        }
    }
}

// =====================================================================
// kv_prep: from qkvbuf fp32 [token][3D] produce
//   Kb[bh][s][d] bf16,  Vt[bh][d][s] bf16 (transposed via LDS tile)
// =====================================================================
__global__ __launch_bounds__(256)
void kv_prep(const float* __restrict__ qkv, ushortT* __restrict__ Kb, ushortT* __restrict__ Vt)
{
    __shared__ ushortT T[64*136];
    const int tid = threadIdx.x;
    const int st = blockIdx.x, bh = blockIdx.y;
    const int b = bh >> 3, h = bh & 7;
    const float* base = qkv + (size_t)(b*SS + st*64)*3*D + h*DHD;

    #pragma unroll
    for (int p = 0; p < 4; ++p) {
        const int row = (tid >> 4) + 16*p;
        const int colb = (tid & 15) * 8;
        {
            const float* src = base + (size_t)row*3*D + D + colb;
            float f[8];
            *reinterpret_cast<float4*>(f)   = *reinterpret_cast<const float4*>(src);
            *reinterpret_cast<float4*>(f+4) = *reinterpret_cast<const float4*>(src+4);
            bf16x8 u;
            #pragma unroll
            for (int e = 0; e < 8; ++e) ((ushortT*)&u)[e] = f2bf(f[e]);
            *reinterpret_cast<bf16x8*>(&Kb[((size_t)bh*SS + st*64 + row)*DHD + colb]) = u;
        }
        {
            const float* src = base + (size_t)row*3*D + 2*D + colb;
            float f[8];
            *reinterpret_cast<float4*>(f)   = *reinterpret_cast<const float4*>(src);
            *reinterpret_cast<float4*>(f+4) = *reinterpret_cast<const float4*>(src+4);
            #pragma unroll
            for (int e = 0; e < 8; ++e) T[row*136 + colb + e] = f2bf(f[e]);
        }
    }
    __syncthreads();
    #pragma unroll
    for (int p = 0; p < 4; ++p) {
        const int d  = (tid >> 3) + 32*p;
        const int sb = (tid & 7) * 8;
        bf16x8 u;
        #pragma unroll
        for (int e = 0; e < 8; ++e) ((ushortT*)&u)[e] = T[(sb + e)*136 + d];
        *reinterpret_cast<bf16x8*>(&Vt[((size_t)bh*DHD + d)*SS + st*64 + sb]) = u;
    }
}

// =====================================================================
// attn_mfma: flash attention, bf16 MFMA, online softmax. bf16 output.
// =====================================================================
#define KLP 136
#define VLP 72
#define PLP 72

__global__ __launch_bounds__(256)
void attn_mfma(const float* __restrict__ qkv, const ushortT* __restrict__ Kb,
               const ushortT* __restrict__ Vt, ushortT* __restrict__ o16)
{
    __shared__ ushortT Kl[64*KLP];
    __shared__ ushortT Vl[128*VLP];
    __shared__ ushortT Pl[4*16*PLP];

    const int tid = threadIdx.x;
    const int w = tid >> 6, lane = tid & 63;
    const int g = lane >> 4, c = lane & 15;
    const int bh = blockIdx.y;
    const int b = bh >> 3, h = bh & 7;
    const int q0 = blockIdx.x*64 + w*16;
    ushortT* Pw = Pl + w*16*PLP;

    bf16x8 qhi[4], qlo[4];
    const float scale = 0.08838834764831845f;
    {
        const float* Qrow = qkv + (size_t)(b*SS + q0 + c)*3*D + h*DHD;
        #pragma unroll
        for (int db = 0; db < 4; ++db) {
            float f[8];
            *reinterpret_cast<float4*>(f)   = *reinterpret_cast<const float4*>(Qrow + db*32 + g*8);
            *reinterpret_cast<float4*>(f+4) = *reinterpret_cast<const float4*>(Qrow + db*32 + g*8 + 4);
            #pragma unroll
            for (int e = 0; e < 8; ++e) {
                const float fs = f[e]*scale;
                const ushortT hi = f2bf(fs);
                ((ushortT*)&qhi[db])[e] = hi;
                ((ushortT*)&qlo[db])[e] = f2bf(fs - bf2f(hi));
            }
        }
    }

    const ushortT* Kg = Kb + (size_t)bh*SS*DHD;
    const ushortT* Vg = Vt + (size_t)bh*DHD*SS;

    float m_r[4], l_r[4];
    #pragma unroll
    for (int r = 0; r < 4; ++r) { m_r[r] = -1e30f; l_r[r] = 0.f; }
    f32x4 oacc[8] = {};

    for (int kt = 0; kt < SS/64; ++kt) {
        __syncthreads();
        #pragma unroll
        for (int p = 0; p < 4; ++p) {
            const int row = (tid >> 4) + 16*p;
            const int colb = (tid & 15)*8;
            bf16x8 u = *reinterpret_cast<const bf16x8*>(&Kg[(size_t)(kt*64 + row)*DHD + colb]);
            *reinterpret_cast<bf16x8*>(&Kl[row*KLP + colb]) = u;
        }
        #pragma unroll
        for (int p = 0; p < 4; ++p) {
            const int dr = (tid >> 3) + 32*p;
            const int sb = (tid & 7)*8;
            bf16x8 u = *reinterpret_cast<const bf16x8*>(&Vg[(size_t)dr*SS + kt*64 + sb]);
            *reinterpret_cast<bf16x8*>(&Vl[dr*VLP + sb]) = u;
        }
        __syncthreads();

        f32x4 s[4] = {};
        #pragma unroll
        for (int db = 0; db < 4; ++db) {
            bf16x8 kf[4];
            #pragma unroll
            for (int kb = 0; kb < 4; ++kb)
                kf[kb] = *reinterpret_cast<const bf16x8*>(&Kl[(kb*16 + c)*KLP + db*32 + g*8]);
            #pragma unroll
            for (int kb = 0; kb < 4; ++kb) {
                s[kb] = __builtin_amdgcn_mfma_f32_16x16x32_bf16(qhi[db], kf[kb], s[kb], 0, 0, 0);
                s[kb] = __builtin_amdgcn_mfma_f32_16x16x32_bf16(qlo[db], kf[kb], s[kb], 0, 0, 0);
            }
        }

        float tmax[4];
        #pragma unroll
        for (int r = 0; r < 4; ++r)
            tmax[r] = fmaxf(fmaxf(s[0][r], s[1][r]), fmaxf(s[2][r], s[3][r]));
        #pragma unroll
        for (int off = 1; off < 16; off <<= 1)
            #pragma unroll
            for (int r = 0; r < 4; ++r)
                tmax[r] = fmaxf(tmax[r], __shfl_xor(tmax[r], off));
        float mn[4], corr[4];
        #pragma unroll
        for (int r = 0; r < 4; ++r) {
            mn[r] = fmaxf(m_r[r], tmax[r]);
            corr[r] = __expf(m_r[r] - mn[r]);
            m_r[r] = mn[r];
        }
        float tsum[4] = {0.f, 0.f, 0.f, 0.f};
        #pragma unroll
        for (int kb = 0; kb < 4; ++kb)
            #pragma unroll
            for (int r = 0; r < 4; ++r) {
                const float p = __expf(s[kb][r] - mn[r]);
                s[kb][r] = p;
                tsum[r] += p;
            }
        #pragma unroll
        for (int off = 1; off < 16; off <<= 1)
            #pragma unroll
            for (int r = 0; r < 4; ++r)
                tsum[r] += __shfl_xor(tsum[r], off);
        #pragma unroll
        for (int r = 0; r < 4; ++r) l_r[r] = l_r[r]*corr[r] + tsum[r];
        #pragma unroll
        for (int df = 0; df < 8; ++df)
            #pragma unroll
            for (int r = 0; r < 4; ++r)
                oacc[df][r] *= corr[r];

        #pragma unroll
        for (int kb = 0; kb < 4; ++kb)
            #pragma unroll
            for (int r = 0; r < 4; ++r)
                Pw[(g*4 + r)*PLP + kb*16 + c] = f2bf(s[kb][r]);

        #pragma unroll
        for (int kk = 0; kk < 2; ++kk) {
            bf16x8 pa = *reinterpret_cast<const bf16x8*>(&Pw[c*PLP + kk*32 + g*8]);
            #pragma unroll
            for (int df = 0; df < 8; ++df) {
                bf16x8 vb = *reinterpret_cast<const bf16x8*>(&Vl[(df*16 + c)*VLP + kk*32 + g*8]);
                oacc[df] = __builtin_amdgcn_mfma_f32_16x16x32_bf16(pa, vb, oacc[df], 0, 0, 0);
            }
        }
    }

    #pragma unroll
    for (int r = 0; r < 4; ++r) {
        const float inv = 1.0f / l_r[r];
        ushortT* orow = o16 + (size_t)(b*SS + q0 + g*4 + r)*D + h*DHD + c;
        #pragma unroll
        for (int df = 0; df < 8; ++df)
            orow[df*16] = f2bf(oacc[df][r] * inv);
    }
}

// =====================================================================
// add_ln_r: xout = LN(xin + sum_s P[s] + dbias) * s + b  (f32 + bf16 out)
// GATE: fused gate softmax top-2 + expert slot-list build (atomics;
// per-token result order-independent -> deterministic output).
// =====================================================================
template<int SK, int GATE>
__global__ __launch_bounds__(256)
void add_ln_r(const float* __restrict__ xin, const float* __restrict__ P,
              const float* __restrict__ dbias,
              const float* __restrict__ gs, const float* __restrict__ gb,
              float* __restrict__ x32, ushortT* __restrict__ x16,
              const float* __restrict__ Wg, const float* __restrict__ bg,
              float* __restrict__ gv, int* __restrict__ slotTok,
              int* __restrict__ tokSlot, int* __restrict__ cntL)
{
    const int row = blockIdx.x, tid = threadIdx.x;
    const size_t off = (size_t)row*D + tid*4;
    float4 a = *reinterpret_cast<const float4*>(xin + off);
    float d0, d1, d2, d3;
    {
        float4 bvd = *reinterpret_cast<const float4*>(dbias + tid*4);
        d0 = bvd.x; d1 = bvd.y; d2 = bvd.z; d3 = bvd.w;
    }
    #pragma unroll
    for (int s = 0; s < SK; ++s) {
        float4 pv = *reinterpret_cast<const float4*>(P + (size_t)s*TT*D + off);
        d0 += pv.x; d1 += pv.y; d2 += pv.z; d3 += pv.w;
    }
    float v0=a.x+d0, v1=a.y+d1, v2=a.z+d2, v3=a.w+d3;
    __shared__ float red[2][4];
    float s = v0+v1+v2+v3;
    #pragma unroll
    for (int o = 32; o; o >>= 1) s += __shfl_xor(s, o, 64);
    if ((tid & 63) == 0) red[0][tid>>6] = s;
    __syncthreads();
    const float mean = (red[0][0]+red[0][1]+red[0][2]+red[0][3]) * (1.0f/D);
    v0-=mean; v1-=mean; v2-=mean; v3-=mean;
    float qv = v0*v0+v1*v1+v2*v2+v3*v3;
    #pragma unroll
    for (int o = 32; o; o >>= 1) qv += __shfl_xor(qv, o, 64);
    if ((tid & 63) == 0) red[1][tid>>6] = qv;
    __syncthreads();
    const float var = (red[1][0]+red[1][1]+red[1][2]+red[1][3]) * (1.0f/D);
    const float rstd = rsqrtf(var + EPSV);
    float4 sv = *reinterpret_cast<const float4*>(gs + tid*4);
    float4 bv = *reinterpret_cast<const float4*>(gb + tid*4);
    float ov[4];
    ov[0] = v0*rstd*sv.x + bv.x;
    ov[1] = v1*rstd*sv.y + bv.y;
    ov[2] = v2*rstd*sv.z + bv.z;
    ov[3] = v3*rstd*sv.w + bv.w;
    float4 o4; o4.x=ov[0]; o4.y=ov[1]; o4.z=ov[2]; o4.w=ov[3];
    *reinterpret_cast<float4*>(x32 + off) = o4;
    ushort4 h4; h4.x=f2bf(ov[0]); h4.y=f2bf(ov[1]); h4.z=f2bf(ov[2]); h4.w=f2bf(ov[3]);
    *reinterpret_cast<ushort4*>(x16 + off) = h4;

    if constexpr (GATE) {
        float p[4] = {0.f, 0.f, 0.f, 0.f};
        #pragma unroll
        for (int e = 0; e < 4; ++e) {
            const float* wr = Wg + (size_t)e*D + tid*4;
            p[e] = ov[0]*wr[0] + ov[1]*wr[1] + ov[2]*wr[2] + ov[3]*wr[3];
        }
        #pragma unroll
        for (int o = 32; o; o >>= 1) {
            p[0] += __shfl_xor(p[0], o, 64); p[1] += __shfl_xor(p[1], o, 64);
            p[2] += __shfl_xor(p[2], o, 64); p[3] += __shfl_xor(p[3], o, 64);
        }
        __shared__ float gred[4][4];
        if ((tid & 63) == 0) {
            const int w = tid>>6;
            gred[w][0]=p[0]; gred[w][1]=p[1]; gred[w][2]=p[2]; gred[w][3]=p[3];
        }
        __syncthreads();
        if (tid == 0) {
            float g[4];
            #pragma unroll
            for (int e = 0; e < 4; ++e) g[e] = gred[0][e]+gred[1][e]+gred[2][e]+gred[3][e] + bg[e];
            const float mx = fmaxf(fmaxf(g[0],g[1]), fmaxf(g[2],g[3]));
            float ssum = 0.f;
            #pragma unroll
            for (int e = 0; e < 4; ++e) { g[e] = __expf(g[e]-mx); ssum += g[e]; }
            const float inv = 1.0f/ssum;
            #pragma unroll
            for (int e = 0; e < 4; ++e) g[e] *= inv;
            int i0 = 0;
            for (int e = 1; e < 4; ++e) if (g[e] > g[i0]) i0 = e;
            int i1 = (i0 == 0) ? 1 : 0;
            for (int e = 0; e < 4; ++e) if (e != i0 && g[e] > g[i1]) i1 = e;
            gv[row*2]   = g[i0]; gv[row*2+1] = g[i1];
            const int p0 = atomicAdd(&cntL[i0], 1);
            slotTok[i0*TT + p0] = row;
            const int p1 = atomicAdd(&cntL[i1], 1);
            slotTok[i1*TT + p1] = row;
            tokSlot[row*2]   = i0*TT + p0;
            tokSlot[row*2+1] = i1*TT + p1;
        }
    }
}

// =====================================================================
__global__ __launch_bounds__(256)
void moe_combine(float* __restrict__ x, ushortT* __restrict__ x16,
                 const float* __restrict__ eo,
                 const float* __restrict__ gv, const int* __restrict__ tokSlot)
{
    const size_t i = (size_t)blockIdx.x*256 + threadIdx.x;
    const int t = (int)(i >> 10);
    const int col = (int)(i & 1023);
    const float w0 = gv[t*2]*SPARS, w1 = gv[t*2+1]*SPARS;
    const float e0 = eo[(size_t)tokSlot[t*2]  *D + col];
    const float e1 = eo[(size_t)tokSlot[t*2+1]*D + col];
    const float r = x[i]*(1.0f-SPARS) + w0*e0 + w1*e1;
    x[i] = r;
    x16[i] = f2bf(r);
}

__global__ __launch_bounds__(256)
void addpos(const float* __restrict__ xin, const float* __restrict__ pos,
            float* __restrict__ xo, ushortT* __restrict__ x16)
{
    const size_t i = (size_t)blockIdx.x*256 + threadIdx.x;
    const float r = xin[i] + pos[i & ((size_t)SS*D - 1)];
    xo[i] = r;
    x16[i] = f2bf(r);
}

__global__ __launch_bounds__(64)
void zero_cnt(int* __restrict__ cnt)
{
    if (threadIdx.x < NL*NE) cnt[threadIdx.x] = 0;
}

__global__ __launch_bounds__(64)
void final_kernel(const float* __restrict__ x, const float* __restrict__ Wf,
                  const float* __restrict__ bf, float* __restrict__ out)
{
    const int b = blockIdx.x / NCLS, n = blockIdx.x % NCLS;
    const float* xr = x + ((size_t)b*SS + SS-1)*D;
    const int tid = threadIdx.x;
    float s = 0.f;
    for (int d = tid; d < D; d += 64) s += xr[d]*Wf[(size_t)n*D + d];
    #pragma unroll
    for (int o = 32; o; o >>= 1) s += __shfl_xor(s, o, 64);
    if (tid == 0) out[b*NCLS + n] = s + bf[n];
}

// =====================================================================
extern "C" void kernel_launch(void* const* d_in, const int* in_sizes, int n_in,
                              void* d_out, int out_size, void* d_ws, size_t ws_size,
                              hipStream_t stream)
{
    const float* x_in = (const float*)d_in[0];
    const float* pos  = (const float*)d_in[1];
    const float* Wqkv = (const float*)d_in[2];
    const float* bqkv = (const float*)d_in[3];
    const float* Wo   = (const float*)d_in[4];
    const float* bo   = (const float*)d_in[5];
    const float* ln1s = (const float*)d_in[6];
    const float* ln1b = (const float*)d_in[7];
    const float* W1   = (const float*)d_in[8];
    const float* b1   = (const float*)d_in[9];
    const float* W2   = (const float*)d_in[10];
    const float* b2   = (const float*)d_in[11];
    const float* ln2s = (const float*)d_in[12];
    const float* ln2b = (const float*)d_in[13];
    const float* Wg   = (const float*)d_in[14];
    const float* bg   = (const float*)d_in[15];
    const float* We   = (const float*)d_in[16];
    const float* be   = (const float*)d_in[17];
    const float* Wf   = (const float*)d_in[18];
    const float* bf   = (const float*)d_in[19];
    float* out = (float*)d_out;

    // ---- workspace layout ----
    float* ws     = (float*)d_ws;
    float*   xbuf  = ws;                                   // TT*D fp32      (8 MB)
    ushortT* xb16  = (ushortT*)(xbuf + (size_t)TT*D);      // TT*D bf16      (4 MB)
    ushortT* ob16  = xb16 + (size_t)TT*D;                  // TT*D bf16      (4 MB) attn out
    float*   scratch = (float*)(ob16 + (size_t)TT*D);      // 4*TT*D floats  (32 MB)
    ushortT* hb16 = (ushortT*)(scratch + (size_t)TT*D*4);  // TT*FF bf16     (8 MB)
    float*   gv    = (float*)(hb16 + (size_t)TT*FF);       // TT*2
    int*     tokSlot = (int*)(gv + (size_t)TT*2);          // TT*2
    int*     slotTok = tokSlot + (size_t)TT*2;             // NE*TT
    int*     cnt     = slotTok + (size_t)NE*TT;            // NL*NE
    // aliases inside scratch (time-disjoint):
    float*   qkvbuf = scratch;                             // TT*3D fp32 (24 MB)
    ushortT* Kb     = (ushortT*)(qkvbuf + (size_t)TT*3*D); // 4 MB
    ushortT* Vt     = Kb + (size_t)BB*NH*SS*DHD;           // 4 MB
    float*   parts  = scratch;                             // 4 x TT*D fp32 (32 MB)
    float*   slotOut = scratch;                            // NE*TT x D fp32 (32 MB)

    const dim3 blk(256);
    zero_cnt<<<dim3(1), dim3(64), 0, stream>>>(cnt);
    addpos<<<dim3(TT*D/256), blk, 0, stream>>>(x_in, pos, xbuf, xb16);

    for (int l = 0; l < NL; ++l) {
        // qkv = x @ Wqkv^T + b  (fp32 out; BN=64 -> 768 blocks, 3/CU)
        gemm_mfma<1,1,0,64,0><<<dim3(3*D/64, TT/128, 1), blk, 0, stream>>>(
            xb16, Wqkv + (size_t)l*3*D*D, bqkv + (size_t)l*3*D, qkvbuf,
            TT, 3*D, D, D, 0, 0, 0, nullptr, nullptr);
        // K/V bf16 prep (V transposed)
        kv_prep<<<dim3(SS/64, BB*NH), blk, 0, stream>>>(qkvbuf, Kb, Vt);
        // flash attention -> ob16 (bf16)
        attn_mfma<<<dim3(SS/64, BB*NH), blk, 0, stream>>>(qkvbuf, Kb, Vt, ob16);
        // o-proj: splitK=4 partials (512 blocks)
        gemm_mfma<1,4,0,128,0><<<dim3(D/128, TT/128, 4), blk, 0, stream>>>(
            ob16, Wo + (size_t)l*D*D, bo, parts, TT, D, D, D/4, 0, 0, 0,
            nullptr, nullptr);
        // x = LN(x + sum(parts) + bo)
        add_ln_r<4,0><<<dim3(TT), blk, 0, stream>>>(
            xbuf, parts, bo + (size_t)l*D, ln1s + (size_t)l*D, ln1b + (size_t)l*D,
            xbuf, xb16, nullptr, nullptr, nullptr, nullptr, nullptr, nullptr);
        // h = gelu(x @ W1^T + b1) -> bf16  (BN=64 -> 512 blocks, 2/CU)
        gemm_mfma<0,1,1,64,0><<<dim3(FF/64, TT/128, 1), blk, 0, stream>>>(
            xb16, W1 + (size_t)l*FF*D, b1 + (size_t)l*FF, hb16, TT, FF, D, D, 0, 0, 0,
            nullptr, nullptr);
        // f2 = h @ W2^T: splitK=4 partials (512 blocks)
        gemm_mfma<1,4,0,128,0><<<dim3(D/128, TT/128, 4), blk, 0, stream>>>(
            hb16, W2 + (size_t)l*D*FF, b2, parts, TT, D, FF, FF/4, 0, 0, 0,
            nullptr, nullptr);
        // x = LN(x + sum(parts) + b2) + fused gate top-2 + slot lists
        add_ln_r<4,1><<<dim3(TT), blk, 0, stream>>>(
            xbuf, parts, b2 + (size_t)l*D, ln2s + (size_t)l*D, ln2b + (size_t)l*D,
            xbuf, xb16, Wg, bg, gv, slotTok, tokSlot, cnt + l*NE);
        // top-2 gathered expert GEMMs (BN=64; blocks past cnt[e] exit early)
        gemm_mfma<1,1,0,64,2><<<dim3(D/64, TT/128, NE), blk, 0, stream>>>(
            xb16, We, be, slotOut, TT, D, D, D, (long)D*D, (long)D, (long)TT*D,
            slotTok, cnt + l*NE);
        // x = x*0.5 + 0.5*(v0*E[slot0] + v1*E[slot1])
        moe_combine<<<dim3(TT*D/256), blk, 0, stream>>>(xbuf, xb16, slotOut, gv, tokSlot);
    }
    final_kernel<<<dim3(BB*NCLS), dim3(64), 0, stream>>>(xbuf, Wf, bf, out);
}

// Round 9
// 2591.290 us; speedup vs baseline: 1.2565x; 1.2565x over previous
//
#include <hip/hip_runtime.h>
#include <math.h>

// ---- problem constants (match reference) ----
#define D     1024
#define NH    8
#define DHD   128
#define NL    12
#define NE    4
#define FF    2048
#define NCLS  10
#define BB    4
#define SS    512
#define TT    (BB*SS)          // 2048 tokens
#define EPSV  1e-5f
#define SPARS 0.5f

typedef __attribute__((ext_vector_type(8))) short bf16x8;
typedef __attribute__((ext_vector_type(4))) float f32x4;
typedef unsigned short ushortT;

__device__ __forceinline__ ushortT f2bf(float f) {
    unsigned u = __float_as_uint(f);
    u += 0x7FFF + ((u >> 16) & 1);      // RNE
    return (ushortT)(u >> 16);
}
__device__ __forceinline__ float bf2f(ushortT h) {
    return __uint_as_float(((unsigned)h) << 16);
}

// =====================================================================
// wconv: fp32 -> bf16 streaming convert (grid-stride, 8 elems/thread)
// =====================================================================
__global__ __launch_bounds__(256)
void wconv(const float* __restrict__ in, ushortT* __restrict__ out, long n)
{
    const long stride = (long)gridDim.x * 256 * 8;
    for (long i = ((long)blockIdx.x * 256 + threadIdx.x) * 8; i < n; i += stride) {
        float f[8];
        *reinterpret_cast<float4*>(f)   = *reinterpret_cast<const float4*>(in + i);
        *reinterpret_cast<float4*>(f+4) = *reinterpret_cast<const float4*>(in + i + 4);
        bf16x8 u;
        #pragma unroll
        for (int e = 0; e < 8; ++e) ((ushortT*)&u)[e] = f2bf(f[e]);
        *reinterpret_cast<bf16x8*>(out + i) = u;
    }
}

// =====================================================================
// MFMA GEMM: C[M,N] = act(A[M,K] @ Bw[N,K]^T + bias[N])
// A bf16 [M][Ktot]; Bw bf16 [N][Ktot] (pre-converted). 128xBN tile,
// BK=32.  BN=128: 4 waves 2x2, 4x4 frags.  BN=64: 4 waves 4x1 (32-row
// slabs), 2x4 frags.
// MODE: 0 = bf16 out, 1 = f32 out.  ACT: 1 = exact GELU.
// SK>1 : blockIdx.z = K-chunk; f32 partials at Cv + z*M*N, no bias/act.
// =====================================================================
#define LDP 40   // LDS row pitch in bf16 elems (32 data + 8 pad)

template<int MODE, int SK, int ACT, int BN>
__global__ __launch_bounds__(256)
void gemm_mfma(const ushortT* __restrict__ A, const ushortT* __restrict__ Bw,
               const float* __restrict__ bias, void* __restrict__ Cv,
               int M, int N, int Ktot, int Klen, long eBw, long eBias, long eC)
{
    const int z = blockIdx.z;
    int koff = 0;
    float* Cf = nullptr; ushortT* Ch = nullptr;
    if constexpr (SK > 1) {
        koff = z * Klen;
        Cf = (float*)Cv + (size_t)z * M * N;
    } else {
        Bw   += (size_t)z * eBw;
        bias += (size_t)z * eBias;
        if constexpr (MODE == 0) Ch = (ushortT*)Cv + (size_t)z * eC;
        else                     Cf = (float*)Cv   + (size_t)z * eC;
    }

    constexpr int MR = (BN == 128) ? 4 : 2;
    __shared__ ushortT Asl[128 * LDP];
    __shared__ ushortT Bsl[BN * LDP];

    const int tid  = threadIdx.x;
    const int wave = tid >> 6, lane = tid & 63;
    const int wm = (BN == 128) ? (wave >> 1) * 64 : wave * 32;
    const int wn = (BN == 128) ? (wave & 1) * 64 : 0;
    const int fr = lane & 15;
    const int fq = lane >> 4;

    const int m0 = blockIdx.y * 128;
    const int n0 = blockIdx.x * BN;

    // A staging: 128 rows x 32 k bf16; 2x bf16x8 per thread
    const int arow = tid >> 1;
    const int akc  = (tid & 1) * 16;
    const ushortT* Ag = A + (size_t)(m0 + arow) * Ktot + koff + akc;
    // B staging: bf16. BN=128: like A (2x bf16x8). BN=64: 1x bf16x8.
    const int brow = (BN == 128) ? (tid >> 1) : (tid >> 2);
    const int bkc  = (BN == 128) ? (tid & 1) * 16 : (tid & 3) * 8;
    const ushortT* Bg = Bw + (size_t)(n0 + brow) * Ktot + koff + bkc;

    f32x4 acc[MR][4] = {};

    for (int k0 = 0; k0 < Klen; k0 += 32) {
        bf16x8 av8[2], bv8[2];
        av8[0] = *reinterpret_cast<const bf16x8*>(Ag + k0);
        av8[1] = *reinterpret_cast<const bf16x8*>(Ag + k0 + 8);
        bv8[0] = *reinterpret_cast<const bf16x8*>(Bg + k0);
        if constexpr (BN == 128)
            bv8[1] = *reinterpret_cast<const bf16x8*>(Bg + k0 + 8);
        __syncthreads();
        *reinterpret_cast<bf16x8*>(&Asl[arow*LDP + akc])     = av8[0];
        *reinterpret_cast<bf16x8*>(&Asl[arow*LDP + akc + 8]) = av8[1];
        *reinterpret_cast<bf16x8*>(&Bsl[brow*LDP + bkc])     = bv8[0];
        if constexpr (BN == 128)
            *reinterpret_cast<bf16x8*>(&Bsl[brow*LDP + bkc + 8]) = bv8[1];
        __syncthreads();

        bf16x8 af[MR], bfr[4];
        #pragma unroll
        for (int i = 0; i < MR; ++i)
            af[i]  = *reinterpret_cast<const bf16x8*>(&Asl[(wm + i*16 + fr)*LDP + fq*8]);
        #pragma unroll
        for (int j = 0; j < 4; ++j)
            bfr[j] = *reinterpret_cast<const bf16x8*>(&Bsl[(wn + j*16 + fr)*LDP + fq*8]);
        #pragma unroll
        for (int i = 0; i < MR; ++i)
            #pragma unroll
            for (int j = 0; j < 4; ++j)
                acc[i][j] = __builtin_amdgcn_mfma_f32_16x16x32_bf16(af[i], bfr[j], acc[i][j], 0, 0, 0);
    }

    #pragma unroll
    for (int j = 0; j < 4; ++j) {
        const int n = n0 + wn + j*16 + fr;
        float bb = 0.f;
        if constexpr (SK == 1) bb = bias[n];
        #pragma unroll
        for (int i = 0; i < MR; ++i) {
            const int mb = m0 + wm + i*16 + fq*4;
            if constexpr (SK > 1) {
                #pragma unroll
                for (int r = 0; r < 4; ++r)
                    Cf[(size_t)(mb + r) * N + n] = acc[i][j][r];
            } else if constexpr (MODE == 0) {
                #pragma unroll
                for (int r = 0; r < 4; ++r) {
                    float u = acc[i][j][r] + bb;
                    if constexpr (ACT == 1) u = 0.5f*u*(1.0f + erff(u*0.70710678118654752f));
                    Ch[(size_t)(mb + r) * N + n] = f2bf(u);
                }
            } else {
                #pragma unroll
                for (int r = 0; r < 4; ++r) {
                    float u = acc[i][j][r] + bb;
                    if constexpr (ACT == 1) u = 0.5f*u*(1.0f + erff(u*0.70710678118654752f));
                    Cf[(size_t)(mb + r) * N + n] = u;
                }
            }
        }
    }
}

// =====================================================================
// kv_prep: from qkvbuf fp32 [token][3D] produce
//   Kb[bh][s][d] bf16,  Vt[bh][d][s] bf16 (transposed via LDS tile)
// =====================================================================
__global__ __launch_bounds__(256)
void kv_prep(const float* __restrict__ qkv, ushortT* __restrict__ Kb, ushortT* __restrict__ Vt)
{
    __shared__ ushortT T[64*136];
    const int tid = threadIdx.x;
    const int st = blockIdx.x, bh = blockIdx.y;
    const int b = bh >> 3, h = bh & 7;
    const float* base = qkv + (size_t)(b*SS + st*64)*3*D + h*DHD;

    #pragma unroll
    for (int p = 0; p < 4; ++p) {
        const int row = (tid >> 4) + 16*p;
        const int colb = (tid & 15) * 8;
        {
            const float* src = base + (size_t)row*3*D + D + colb;
            float f[8];
            *reinterpret_cast<float4*>(f)   = *reinterpret_cast<const float4*>(src);
            *reinterpret_cast<float4*>(f+4) = *reinterpret_cast<const float4*>(src+4);
            bf16x8 u;
            #pragma unroll
            for (int e = 0; e < 8; ++e) ((ushortT*)&u)[e] = f2bf(f[e]);
            *reinterpret_cast<bf16x8*>(&Kb[((size_t)bh*SS + st*64 + row)*DHD + colb]) = u;
        }
        {
            const float* src = base + (size_t)row*3*D + 2*D + colb;
            float f[8];
            *reinterpret_cast<float4*>(f)   = *reinterpret_cast<const float4*>(src);
            *reinterpret_cast<float4*>(f+4) = *reinterpret_cast<const float4*>(src+4);
            #pragma unroll
            for (int e = 0; e < 8; ++e) T[row*136 + colb + e] = f2bf(f[e]);
        }
    }
    __syncthreads();
    #pragma unroll
    for (int p = 0; p < 4; ++p) {
        const int d  = (tid >> 3) + 32*p;
        const int sb = (tid & 7) * 8;
        bf16x8 u;
        #pragma unroll
        for (int e = 0; e < 8; ++e) ((ushortT*)&u)[e] = T[(sb + e)*136 + d];
        *reinterpret_cast<bf16x8*>(&Vt[((size_t)bh*DHD + d)*SS + st*64 + sb]) = u;
    }
}

// =====================================================================
// attn_mfma: flash attention, bf16 MFMA, online softmax. bf16 output.
// =====================================================================
#define KLP 136
#define VLP 72
#define PLP 72

__global__ __launch_bounds__(256)
void attn_mfma(const float* __restrict__ qkv, const ushortT* __restrict__ Kb,
               const ushortT* __restrict__ Vt, ushortT* __restrict__ o16)
{
    __shared__ ushortT Kl[64*KLP];
    __shared__ ushortT Vl[128*VLP];
    __shared__ ushortT Pl[4*16*PLP];

    const int tid = threadIdx.x;
    const int w = tid >> 6, lane = tid & 63;
    const int g = lane >> 4, c = lane & 15;
    const int bh = blockIdx.y;
    const int b = bh >> 3, h = bh & 7;
    const int q0 = blockIdx.x*64 + w*16;
    ushortT* Pw = Pl + w*16*PLP;

    bf16x8 qhi[4], qlo[4];
    const float scale = 0.08838834764831845f;
    {
        const float* Qrow = qkv + (size_t)(b*SS + q0 + c)*3*D + h*DHD;
        #pragma unroll
        for (int db = 0; db < 4; ++db) {
            float f[8];
            *reinterpret_cast<float4*>(f)   = *reinterpret_cast<const float4*>(Qrow + db*32 + g*8);
            *reinterpret_cast<float4*>(f+4) = *reinterpret_cast<const float4*>(Qrow + db*32 + g*8 + 4);
            #pragma unroll
            for (int e = 0; e < 8; ++e) {
                const float fs = f[e]*scale;
                const ushortT hi = f2bf(fs);
                ((ushortT*)&qhi[db])[e] = hi;
                ((ushortT*)&qlo[db])[e] = f2bf(fs - bf2f(hi));
            }
        }
    }

    const ushortT* Kg = Kb + (size_t)bh*SS*DHD;
    const ushortT* Vg = Vt + (size_t)bh*DHD*SS;

    float m_r[4], l_r[4];
    #pragma unroll
    for (int r = 0; r < 4; ++r) { m_r[r] = -1e30f; l_r[r] = 0.f; }
    f32x4 oacc[8] = {};

    for (int kt = 0; kt < SS/64; ++kt) {
        __syncthreads();
        #pragma unroll
        for (int p = 0; p < 4; ++p) {
            const int row = (tid >> 4) + 16*p;
            const int colb = (tid & 15)*8;
            bf16x8 u = *reinterpret_cast<const bf16x8*>(&Kg[(size_t)(kt*64 + row)*DHD + colb]);
            *reinterpret_cast<bf16x8*>(&Kl[row*KLP + colb]) = u;
        }
        #pragma unroll
        for (int p = 0; p < 4; ++p) {
            const int dr = (tid >> 3) + 32*p;
            const int sb = (tid & 7)*8;
            bf16x8 u = *reinterpret_cast<const bf16x8*>(&Vg[(size_t)dr*SS + kt*64 + sb]);
            *reinterpret_cast<bf16x8*>(&Vl[dr*VLP + sb]) = u;
        }
        __syncthreads();

        f32x4 s[4] = {};
        #pragma unroll
        for (int db = 0; db < 4; ++db) {
            bf16x8 kf[4];
            #pragma unroll
            for (int kb = 0; kb < 4; ++kb)
                kf[kb] = *reinterpret_cast<const bf16x8*>(&Kl[(kb*16 + c)*KLP + db*32 + g*8]);
            #pragma unroll
            for (int kb = 0; kb < 4; ++kb) {
                s[kb] = __builtin_amdgcn_mfma_f32_16x16x32_bf16(qhi[db], kf[kb], s[kb], 0, 0, 0);
                s[kb] = __builtin_amdgcn_mfma_f32_16x16x32_bf16(qlo[db], kf[kb], s[kb], 0, 0, 0);
            }
        }

        float tmax[4];
        #pragma unroll
        for (int r = 0; r < 4; ++r)
            tmax[r] = fmaxf(fmaxf(s[0][r], s[1][r]), fmaxf(s[2][r], s[3][r]));
        #pragma unroll
        for (int off = 1; off < 16; off <<= 1)
            #pragma unroll
            for (int r = 0; r < 4; ++r)
                tmax[r] = fmaxf(tmax[r], __shfl_xor(tmax[r], off));
        float mn[4], corr[4];
        #pragma unroll
        for (int r = 0; r < 4; ++r) {
            mn[r] = fmaxf(m_r[r], tmax[r]);
            corr[r] = __expf(m_r[r] - mn[r]);
            m_r[r] = mn[r];
        }
        float tsum[4] = {0.f, 0.f, 0.f, 0.f};
        #pragma unroll
        for (int kb = 0; kb < 4; ++kb)
            #pragma unroll
            for (int r = 0; r < 4; ++r) {
                const float p = __expf(s[kb][r] - mn[r]);
                s[kb][r] = p;
                tsum[r] += p;
            }
        #pragma unroll
        for (int off = 1; off < 16; off <<= 1)
            #pragma unroll
            for (int r = 0; r < 4; ++r)
                tsum[r] += __shfl_xor(tsum[r], off);
        #pragma unroll
        for (int r = 0; r < 4; ++r) l_r[r] = l_r[r]*corr[r] + tsum[r];
        #pragma unroll
        for (int df = 0; df < 8; ++df)
            #pragma unroll
            for (int r = 0; r < 4; ++r)
                oacc[df][r] *= corr[r];

        #pragma unroll
        for (int kb = 0; kb < 4; ++kb)
            #pragma unroll
            for (int r = 0; r < 4; ++r)
                Pw[(g*4 + r)*PLP + kb*16 + c] = f2bf(s[kb][r]);

        #pragma unroll
        for (int kk = 0; kk < 2; ++kk) {
            bf16x8 pa = *reinterpret_cast<const bf16x8*>(&Pw[c*PLP + kk*32 + g*8]);
            #pragma unroll
            for (int df = 0; df < 8; ++df) {
                bf16x8 vb = *reinterpret_cast<const bf16x8*>(&Vl[(df*16 + c)*VLP + kk*32 + g*8]);
                oacc[df] = __builtin_amdgcn_mfma_f32_16x16x32_bf16(pa, vb, oacc[df], 0, 0, 0);
            }
        }
    }

    #pragma unroll
    for (int r = 0; r < 4; ++r) {
        const float inv = 1.0f / l_r[r];
        ushortT* orow = o16 + (size_t)(b*SS + q0 + g*4 + r)*D + h*DHD + c;
        #pragma unroll
        for (int df = 0; df < 8; ++df)
            orow[df*16] = f2bf(oacc[df][r] * inv);
    }
}

// =====================================================================
// add_ln_r: xout = LN(xin + sum_s P[s] + dbias) * s + b  (f32 + bf16 out)
// GATE: also computes gate softmax top-2.
// =====================================================================
template<int SK, int GATE>
__global__ __launch_bounds__(256)
void add_ln_r(const float* __restrict__ xin, const float* __restrict__ P,
              const float* __restrict__ dbias,
              const float* __restrict__ gs, const float* __restrict__ gb,
              float* __restrict__ x32, ushortT* __restrict__ x16,
              const float* __restrict__ Wg, const float* __restrict__ bg,
              float* __restrict__ gv, int* __restrict__ gi)
{
    const int row = blockIdx.x, tid = threadIdx.x;
    const size_t off = (size_t)row*D + tid*4;
    float4 a = *reinterpret_cast<const float4*>(xin + off);
    float d0, d1, d2, d3;
    {
        float4 bvd = *reinterpret_cast<const float4*>(dbias + tid*4);
        d0 = bvd.x; d1 = bvd.y; d2 = bvd.z; d3 = bvd.w;
    }
    #pragma unroll
    for (int s = 0; s < SK; ++s) {
        float4 pv = *reinterpret_cast<const float4*>(P + (size_t)s*TT*D + off);
        d0 += pv.x; d1 += pv.y; d2 += pv.z; d3 += pv.w;
    }
    float v0=a.x+d0, v1=a.y+d1, v2=a.z+d2, v3=a.w+d3;
    __shared__ float red[2][4];
    float s = v0+v1+v2+v3;
    #pragma unroll
    for (int o = 32; o; o >>= 1) s += __shfl_xor(s, o, 64);
    if ((tid & 63) == 0) red[0][tid>>6] = s;
    __syncthreads();
    const float mean = (red[0][0]+red[0][1]+red[0][2]+red[0][3]) * (1.0f/D);
    v0-=mean; v1-=mean; v2-=mean; v3-=mean;
    float qv = v0*v0+v1*v1+v2*v2+v3*v3;
    #pragma unroll
    for (int o = 32; o; o >>= 1) qv += __shfl_xor(qv, o, 64);
    if ((tid & 63) == 0) red[1][tid>>6] = qv;
    __syncthreads();
    const float var = (red[1][0]+red[1][1]+red[1][2]+red[1][3]) * (1.0f/D);
    const float rstd = rsqrtf(var + EPSV);
    float4 sv = *reinterpret_cast<const float4*>(gs + tid*4);
    float4 bv = *reinterpret_cast<const float4*>(gb + tid*4);
    float ov[4];
    ov[0] = v0*rstd*sv.x + bv.x;
    ov[1] = v1*rstd*sv.y + bv.y;
    ov[2] = v2*rstd*sv.z + bv.z;
    ov[3] = v3*rstd*sv.w + bv.w;
    float4 o4; o4.x=ov[0]; o4.y=ov[1]; o4.z=ov[2]; o4.w=ov[3];
    *reinterpret_cast<float4*>(x32 + off) = o4;
    ushort4 h4; h4.x=f2bf(ov[0]); h4.y=f2bf(ov[1]); h4.z=f2bf(ov[2]); h4.w=f2bf(ov[3]);
    *reinterpret_cast<ushort4*>(x16 + off) = h4;

    if constexpr (GATE) {
        float p[4] = {0.f, 0.f, 0.f, 0.f};
        #pragma unroll
        for (int e = 0; e < 4; ++e) {
            const float* wr = Wg + (size_t)e*D + tid*4;
            p[e] = ov[0]*wr[0] + ov[1]*wr[1] + ov[2]*wr[2] + ov[3]*wr[3];
        }
        #pragma unroll
        for (int o = 32; o; o >>= 1) {
            p[0] += __shfl_xor(p[0], o, 64); p[1] += __shfl_xor(p[1], o, 64);
            p[2] += __shfl_xor(p[2], o, 64); p[3] += __shfl_xor(p[3], o, 64);
        }
        __shared__ float gred[4][4];
        if ((tid & 63) == 0) {
            const int w = tid>>6;
            gred[w][0]=p[0]; gred[w][1]=p[1]; gred[w][2]=p[2]; gred[w][3]=p[3];
        }
        __syncthreads();
        if (tid == 0) {
            float g[4];
            #pragma unroll
            for (int e = 0; e < 4; ++e) g[e] = gred[0][e]+gred[1][e]+gred[2][e]+gred[3][e] + bg[e];
            const float mx = fmaxf(fmaxf(g[0],g[1]), fmaxf(g[2],g[3]));
            float ssum = 0.f;
            #pragma unroll
            for (int e = 0; e < 4; ++e) { g[e] = __expf(g[e]-mx); ssum += g[e]; }
            const float inv = 1.0f/ssum;
            #pragma unroll
            for (int e = 0; e < 4; ++e) g[e] *= inv;
            int i0 = 0;
            for (int e = 1; e < 4; ++e) if (g[e] > g[i0]) i0 = e;
            int i1 = (i0 == 0) ? 1 : 0;
            for (int e = 0; e < 4; ++e) if (e != i0 && g[e] > g[i1]) i1 = e;
            gv[row*2]   = g[i0]; gv[row*2+1] = g[i1];
            gi[row*2]   = i0;    gi[row*2+1] = i1;
        }
    }
}

// =====================================================================
__global__ __launch_bounds__(256)
void moe_combine(float* __restrict__ x, ushortT* __restrict__ x16,
                 const float* __restrict__ eo,
                 const float* __restrict__ gv, const int* __restrict__ gi)
{
    const size_t i = (size_t)blockIdx.x*256 + threadIdx.x;
    const int t = (int)(i >> 10);
    const float w0 = gv[t*2]*SPARS, w1 = gv[t*2+1]*SPARS;
    const size_t TD = (size_t)TT*D;
    const float e0 = eo[(size_t)gi[t*2]*TD + i];
    const float e1 = eo[(size_t)gi[t*2+1]*TD + i];
    const float r = x[i]*(1.0f-SPARS) + w0*e0 + w1*e1;
    x[i] = r;
    x16[i] = f2bf(r);
}

__global__ __launch_bounds__(256)
void addpos(const float* __restrict__ xin, const float* __restrict__ pos,
            float* __restrict__ xo, ushortT* __restrict__ x16)
{
    const size_t i = (size_t)blockIdx.x*256 + threadIdx.x;
    const float r = xin[i] + pos[i & ((size_t)SS*D - 1)];
    xo[i] = r;
    x16[i] = f2bf(r);
}

__global__ __launch_bounds__(64)
void final_kernel(const float* __restrict__ x, const float* __restrict__ Wf,
                  const float* __restrict__ bf, float* __restrict__ out)
{
    const int b = blockIdx.x / NCLS, n = blockIdx.x % NCLS;
    const float* xr = x + ((size_t)b*SS + SS-1)*D;
    const int tid = threadIdx.x;
    float s = 0.f;
    for (int d = tid; d < D; d += 64) s += xr[d]*Wf[(size_t)n*D + d];
    #pragma unroll
    for (int o = 32; o; o >>= 1) s += __shfl_xor(s, o, 64);
    if (tid == 0) out[b*NCLS + n] = s + bf[n];
}

// =====================================================================
extern "C" void kernel_launch(void* const* d_in, const int* in_sizes, int n_in,
                              void* d_out, int out_size, void* d_ws, size_t ws_size,
                              hipStream_t stream)
{
    const float* x_in = (const float*)d_in[0];
    const float* pos  = (const float*)d_in[1];
    const float* Wqkv = (const float*)d_in[2];
    const float* bqkv = (const float*)d_in[3];
    const float* Wo   = (const float*)d_in[4];
    const float* bo   = (const float*)d_in[5];
    const float* ln1s = (const float*)d_in[6];
    const float* ln1b = (const float*)d_in[7];
    const float* W1   = (const float*)d_in[8];
    const float* b1   = (const float*)d_in[9];
    const float* W2   = (const float*)d_in[10];
    const float* b2   = (const float*)d_in[11];
    const float* ln2s = (const float*)d_in[12];
    const float* ln2b = (const float*)d_in[13];
    const float* Wg   = (const float*)d_in[14];
    const float* bg   = (const float*)d_in[15];
    const float* We   = (const float*)d_in[16];
    const float* be   = (const float*)d_in[17];
    const float* Wf   = (const float*)d_in[18];
    const float* bf   = (const float*)d_in[19];
    float* out = (float*)d_out;

    // ---- weight element counts ----
    const long nWqkv = (long)NL*3*D*D;   // 37,748,736
    const long nWo   = (long)NL*D*D;     // 12,582,912
    const long nW1   = (long)NL*FF*D;    // 25,165,824
    const long nW2   = (long)NL*D*FF;    // 25,165,824
    const long nWe   = (long)NE*D*D;     //  4,194,304

    // ---- workspace layout (round-7 proven + bf16 weight cache) ----
    float* ws     = (float*)d_ws;
    float*   xbuf  = ws;                                   // TT*D fp32      (8 MB)
    ushortT* xb16  = (ushortT*)(xbuf + (size_t)TT*D);      // TT*D bf16      (4 MB)
    ushortT* ob16  = xb16 + (size_t)TT*D;                  // TT*D bf16      (4 MB)
    float*   scratch = (float*)(ob16 + (size_t)TT*D);      // 4*TT*D floats  (32 MB)
    ushortT* hb16 = (ushortT*)(scratch + (size_t)TT*D*4);  // TT*FF bf16     (8 MB)
    float*   gv    = (float*)(hb16 + (size_t)TT*FF);       // TT*2
    int*     gi    = (int*)(gv + (size_t)TT*2);            // TT*2
    ushortT* wq16  = (ushortT*)(gi + (size_t)TT*2);        // bf16 weights (200 MB)
    ushortT* wo16  = wq16 + nWqkv;
    ushortT* w116  = wo16 + nWo;
    ushortT* w216  = w116 + nW1;
    ushortT* we16  = w216 + nW2;
    // aliases inside scratch (time-disjoint):
    float*   qkvbuf = scratch;                             // TT*3D fp32 (24 MB)
    ushortT* Kb     = (ushortT*)(qkvbuf + (size_t)TT*3*D); // 4 MB
    ushortT* Vt     = Kb + (size_t)BB*NH*SS*DHD;           // 4 MB
    float*   parts  = scratch;                             // 4 x TT*D fp32 (32 MB)
    float*   ebuf   = scratch;                             // 4 x TT*D fp32 (32 MB)

    const dim3 blk(256);
    // one-time (per call) fp32 -> bf16 weight conversion (RNE, identical
    // rounding to previous in-staging convert -> bitwise-identical output)
    wconv<<<dim3(2048), blk, 0, stream>>>(Wqkv, wq16, nWqkv);
    wconv<<<dim3(1024), blk, 0, stream>>>(Wo,   wo16, nWo);
    wconv<<<dim3(2048), blk, 0, stream>>>(W1,   w116, nW1);
    wconv<<<dim3(2048), blk, 0, stream>>>(W2,   w216, nW2);
    wconv<<<dim3(512),  blk, 0, stream>>>(We,   we16, nWe);

    addpos<<<dim3(TT*D/256), blk, 0, stream>>>(x_in, pos, xbuf, xb16);

    for (int l = 0; l < NL; ++l) {
        // qkv = x @ Wqkv^T + b  (fp32 out; BN=64 -> 768 blocks, 3/CU)
        gemm_mfma<1,1,0,64><<<dim3(3*D/64, TT/128, 1), blk, 0, stream>>>(
            xb16, wq16 + (size_t)l*3*D*D, bqkv + (size_t)l*3*D, qkvbuf,
            TT, 3*D, D, D, 0, 0, 0);
        // K/V bf16 prep (V transposed)
        kv_prep<<<dim3(SS/64, BB*NH), blk, 0, stream>>>(qkvbuf, Kb, Vt);
        // flash attention -> ob16 (bf16)
        attn_mfma<<<dim3(SS/64, BB*NH), blk, 0, stream>>>(qkvbuf, Kb, Vt, ob16);
        // o-proj: splitK=4 partials (512 blocks)
        gemm_mfma<1,4,0,128><<<dim3(D/128, TT/128, 4), blk, 0, stream>>>(
            ob16, wo16 + (size_t)l*D*D, bo, parts, TT, D, D, D/4, 0, 0, 0);
        // x = LN(x + sum(parts) + bo)
        add_ln_r<4,0><<<dim3(TT), blk, 0, stream>>>(
            xbuf, parts, bo + (size_t)l*D, ln1s + (size_t)l*D, ln1b + (size_t)l*D,
            xbuf, xb16, nullptr, nullptr, nullptr, nullptr);
        // h = gelu(x @ W1^T + b1) -> bf16  (BN=64 -> 512 blocks, 2/CU)
        gemm_mfma<0,1,1,64><<<dim3(FF/64, TT/128, 1), blk, 0, stream>>>(
            xb16, w116 + (size_t)l*FF*D, b1 + (size_t)l*FF, hb16, TT, FF, D, D, 0, 0, 0);
        // f2 = h @ W2^T: splitK=4 partials (512 blocks)
        gemm_mfma<1,4,0,128><<<dim3(D/128, TT/128, 4), blk, 0, stream>>>(
            hb16, w216 + (size_t)l*D*FF, b2, parts, TT, D, FF, FF/4, 0, 0, 0);
        // x = LN(x + sum(parts) + b2) + fused gate top-2
        add_ln_r<4,1><<<dim3(TT), blk, 0, stream>>>(
            xbuf, parts, b2 + (size_t)l*D, ln2s + (size_t)l*D, ln2b + (size_t)l*D,
            xbuf, xb16, Wg, bg, gv, gi);
        // all 4 expert outputs in ONE launch (BN=64 -> 1024 blocks, 4/CU)
        gemm_mfma<1,1,0,64><<<dim3(D/64, TT/128, NE), blk, 0, stream>>>(
            xb16, we16, be, ebuf, TT, D, D, D, (long)D*D, (long)D, (long)TT*D);
        // x = x*0.5 + 0.5*(v0*E0 + v1*E1)
        moe_combine<<<dim3(TT*D/256), blk, 0, stream>>>(xbuf, xb16, ebuf, gv, gi);
    }
    final_kernel<<<dim3(BB*NCLS), dim3(64), 0, stream>>>(xbuf, Wf, bf, out);
}

// Round 10
// 2421.903 us; speedup vs baseline: 1.3443x; 1.0699x over previous
//
#include <hip/hip_runtime.h>
#include <math.h>

// ---- problem constants (match reference) ----
#define D     1024
#define NH    8
#define DHD   128
#define NL    12
#define NE    4
#define FF    2048
#define NCLS  10
#define BB    4
#define SS    512
#define TT    (BB*SS)          // 2048 tokens
#define EPSV  1e-5f
#define SPARS 0.5f

typedef __attribute__((ext_vector_type(8))) short bf16x8;
typedef __attribute__((ext_vector_type(4))) float f32x4;
typedef unsigned short ushortT;

__device__ __forceinline__ ushortT f2bf(float f) {
    unsigned u = __float_as_uint(f);
    u += 0x7FFF + ((u >> 16) & 1);      // RNE
    return (ushortT)(u >> 16);
}
__device__ __forceinline__ float bf2f(ushortT h) {
    return __uint_as_float(((unsigned)h) << 16);
}

// =====================================================================
// wconv: fp32 -> bf16 streaming convert (grid-stride, 8 elems/thread)
// =====================================================================
__global__ __launch_bounds__(256)
void wconv(const float* __restrict__ in, ushortT* __restrict__ out, long n)
{
    const long stride = (long)gridDim.x * 256 * 8;
    for (long i = ((long)blockIdx.x * 256 + threadIdx.x) * 8; i < n; i += stride) {
        float f[8];
        *reinterpret_cast<float4*>(f)   = *reinterpret_cast<const float4*>(in + i);
        *reinterpret_cast<float4*>(f+4) = *reinterpret_cast<const float4*>(in + i + 4);
        bf16x8 u;
        #pragma unroll
        for (int e = 0; e < 8; ++e) ((ushortT*)&u)[e] = f2bf(f[e]);
        *reinterpret_cast<bf16x8*>(out + i) = u;
    }
}

// =====================================================================
// MFMA GEMM: C[M,N] = act(A[M,K] @ Bw[N,K]^T + bias[N])
// A bf16 [M][Ktot]; Bw bf16 [N][Ktot] (pre-converted). 128xBN tile,
// BK=32, reg-double-buffered staging (next tile's loads issued before
// the MFMA section so HBM latency hides under compute).
// MODE: 0 = bf16 out, 1 = f32 out.  ACT: 1 = exact GELU.
// SK>1 : blockIdx.z = K-chunk; f32 partials at Cv + z*M*N, no bias/act.
// EPI 0: standard.
// EPI 1: qkv split epilogue -> Q f32 [tok][D], K bf16 [bh][s][d],
//        V bf16 [tok][D]  (all coalesced row-major-class writes)
// =====================================================================
#define LDP 40   // LDS row pitch in bf16 elems (32 data + 8 pad)

template<int MODE, int SK, int ACT, int BN, int EPI>
__global__ __launch_bounds__(256)
void gemm_mfma(const ushortT* __restrict__ A, const ushortT* __restrict__ Bw,
               const float* __restrict__ bias, void* __restrict__ Cv,
               int M, int N, int Ktot, int Klen, long eBw, long eBias, long eC,
               float* __restrict__ qp, ushortT* __restrict__ kp, ushortT* __restrict__ vp)
{
    const int z = blockIdx.z;
    int koff = 0;
    float* Cf = nullptr; ushortT* Ch = nullptr;
    if constexpr (SK > 1) {
        koff = z * Klen;
        Cf = (float*)Cv + (size_t)z * M * N;
    } else {
        Bw   += (size_t)z * eBw;
        bias += (size_t)z * eBias;
        if constexpr (MODE == 0) Ch = (ushortT*)Cv + (size_t)z * eC;
        else                     Cf = (float*)Cv   + (size_t)z * eC;
    }

    constexpr int MR = (BN == 128) ? 4 : 2;
    __shared__ ushortT Asl[128 * LDP];
    __shared__ ushortT Bsl[BN * LDP];

    const int tid  = threadIdx.x;
    const int wave = tid >> 6, lane = tid & 63;
    const int wm = (BN == 128) ? (wave >> 1) * 64 : wave * 32;
    const int wn = (BN == 128) ? (wave & 1) * 64 : 0;
    const int fr = lane & 15;
    const int fq = lane >> 4;

    const int m0 = blockIdx.y * 128;
    const int n0 = blockIdx.x * BN;

    // A staging: 128 rows x 32 k bf16; 2x bf16x8 per thread
    const int arow = tid >> 1;
    const int akc  = (tid & 1) * 16;
    const ushortT* Ag = A + (size_t)(m0 + arow) * Ktot + koff + akc;
    // B staging: bf16. BN=128: 2x bf16x8. BN=64: 1x bf16x8.
    const int brow = (BN == 128) ? (tid >> 1) : (tid >> 2);
    const int bkc  = (BN == 128) ? (tid & 1) * 16 : (tid & 3) * 8;
    const ushortT* Bg = Bw + (size_t)(n0 + brow) * Ktot + koff + bkc;

    f32x4 acc[MR][4] = {};
    bf16x8 av8[2], bv8[2];

    // prologue: load k=0 tile into registers
    av8[0] = *reinterpret_cast<const bf16x8*>(Ag);
    av8[1] = *reinterpret_cast<const bf16x8*>(Ag + 8);
    bv8[0] = *reinterpret_cast<const bf16x8*>(Bg);
    if constexpr (BN == 128)
        bv8[1] = *reinterpret_cast<const bf16x8*>(Bg + 8);

    for (int k0 = 0; k0 < Klen; k0 += 32) {
        __syncthreads();    // previous iteration's frag reads complete
        *reinterpret_cast<bf16x8*>(&Asl[arow*LDP + akc])     = av8[0];
        *reinterpret_cast<bf16x8*>(&Asl[arow*LDP + akc + 8]) = av8[1];
        *reinterpret_cast<bf16x8*>(&Bsl[brow*LDP + bkc])     = bv8[0];
        if constexpr (BN == 128)
            *reinterpret_cast<bf16x8*>(&Bsl[brow*LDP + bkc + 8]) = bv8[1];
        __syncthreads();

        const int kn = k0 + 32;
        if (kn < Klen) {     // issue next-tile loads; latency hides under MFMA
            av8[0] = *reinterpret_cast<const bf16x8*>(Ag + kn);
            av8[1] = *reinterpret_cast<const bf16x8*>(Ag + kn + 8);
            bv8[0] = *reinterpret_cast<const bf16x8*>(Bg + kn);
            if constexpr (BN == 128)
                bv8[1] = *reinterpret_cast<const bf16x8*>(Bg + kn + 8);
        }

        bf16x8 af[MR], bfr[4];
        #pragma unroll
        for (int i = 0; i < MR; ++i)
            af[i]  = *reinterpret_cast<const bf16x8*>(&Asl[(wm + i*16 + fr)*LDP + fq*8]);
        #pragma unroll
        for (int j = 0; j < 4; ++j)
            bfr[j] = *reinterpret_cast<const bf16x8*>(&Bsl[(wn + j*16 + fr)*LDP + fq*8]);
        #pragma unroll
        for (int i = 0; i < MR; ++i)
            #pragma unroll
            for (int j = 0; j < 4; ++j)
                acc[i][j] = __builtin_amdgcn_mfma_f32_16x16x32_bf16(af[i], bfr[j], acc[i][j], 0, 0, 0);
    }

    #pragma unroll
    for (int j = 0; j < 4; ++j) {
        const int n = n0 + wn + j*16 + fr;
        float bb = 0.f;
        if constexpr (SK == 1) bb = bias[n];
        #pragma unroll
        for (int i = 0; i < MR; ++i) {
            const int mb = m0 + wm + i*16 + fq*4;
            if constexpr (EPI == 1) {
                #pragma unroll
                for (int r = 0; r < 4; ++r) {
                    const float u = acc[i][j][r] + bb;
                    const int t = mb + r;                    // token
                    if (n0 < D) {
                        qp[(size_t)t*D + n] = u;             // Q fp32 [tok][D]
                    } else if (n0 < 2*D) {
                        const int n2 = n - D;
                        const int hh = n2 >> 7, dd = n2 & 127;
                        const int bb_ = t >> 9, ss_ = t & 511;
                        kp[(((size_t)bb_*NH + hh)*SS + ss_)*DHD + dd] = f2bf(u);
                    } else {
                        vp[(size_t)t*D + (n - 2*D)] = f2bf(u);  // V bf16 [tok][D]
                    }
                }
            } else if constexpr (SK > 1) {
                #pragma unroll
                for (int r = 0; r < 4; ++r)
                    Cf[(size_t)(mb + r) * N + n] = acc[i][j][r];
            } else if constexpr (MODE == 0) {
                #pragma unroll
                for (int r = 0; r < 4; ++r) {
                    float u = acc[i][j][r] + bb;
                    if constexpr (ACT == 1) u = 0.5f*u*(1.0f + erff(u*0.70710678118654752f));
                    Ch[(size_t)(mb + r) * N + n] = f2bf(u);
                }
            } else {
                #pragma unroll
                for (int r = 0; r < 4; ++r) {
                    float u = acc[i][j][r] + bb;
                    if constexpr (ACT == 1) u = 0.5f*u*(1.0f + erff(u*0.70710678118654752f));
                    Cf[(size_t)(mb + r) * N + n] = u;
                }
            }
        }
    }
}

// =====================================================================
// v_tr: transpose V bf16 [token][D] -> Vt bf16 [bh][d][s] (LDS tile)
// =====================================================================
__global__ __launch_bounds__(256)
void v_tr(const ushortT* __restrict__ Vb, ushortT* __restrict__ Vt)
{
    __shared__ ushortT T[64*136];
    const int tid = threadIdx.x;
    const int st = blockIdx.x, bh = blockIdx.y;
    const int b = bh >> 3, h = bh & 7;
    const ushortT* base = Vb + (size_t)(b*SS + st*64)*D + h*DHD;

    #pragma unroll
    for (int p = 0; p < 4; ++p) {
        const int row = (tid >> 4) + 16*p;        // s within tile
        const int colb = (tid & 15) * 8;          // d
        bf16x8 u = *reinterpret_cast<const bf16x8*>(base + (size_t)row*D + colb);
        *reinterpret_cast<bf16x8*>(&T[row*136 + colb]) = u;
    }
    __syncthreads();
    #pragma unroll
    for (int p = 0; p < 4; ++p) {
        const int d  = (tid >> 3) + 32*p;         // 0..127
        const int sb = (tid & 7) * 8;             // 0..56
        bf16x8 u;
        #pragma unroll
        for (int e = 0; e < 8; ++e) ((ushortT*)&u)[e] = T[(sb + e)*136 + d];
        *reinterpret_cast<bf16x8*>(&Vt[((size_t)bh*DHD + d)*SS + st*64 + sb]) = u;
    }
}

// =====================================================================
// attn_mfma: flash attention, bf16 MFMA, online softmax. bf16 output.
// Q fp32 [tok][D]; K bf16 [bh][s][d]; V bf16 transposed [bh][d][s].
// =====================================================================
#define KLP 136
#define VLP 72
#define PLP 72

__global__ __launch_bounds__(256)
void attn_mfma(const float* __restrict__ Qb, const ushortT* __restrict__ Kb,
               const ushortT* __restrict__ Vt, ushortT* __restrict__ o16)
{
    __shared__ ushortT Kl[64*KLP];
    __shared__ ushortT Vl[128*VLP];
    __shared__ ushortT Pl[4*16*PLP];

    const int tid = threadIdx.x;
    const int w = tid >> 6, lane = tid & 63;
    const int g = lane >> 4, c = lane & 15;
    const int bh = blockIdx.y;
    const int b = bh >> 3, h = bh & 7;
    const int q0 = blockIdx.x*64 + w*16;
    ushortT* Pw = Pl + w*16*PLP;

    bf16x8 qhi[4], qlo[4];
    const float scale = 0.08838834764831845f;
    {
        const float* Qrow = Qb + (size_t)(b*SS + q0 + c)*D + h*DHD;
        #pragma unroll
        for (int db = 0; db < 4; ++db) {
            float f[8];
            *reinterpret_cast<float4*>(f)   = *reinterpret_cast<const float4*>(Qrow + db*32 + g*8);
            *reinterpret_cast<float4*>(f+4) = *reinterpret_cast<const float4*>(Qrow + db*32 + g*8 + 4);
            #pragma unroll
            for (int e = 0; e < 8; ++e) {
                const float fs = f[e]*scale;
                const ushortT hi = f2bf(fs);
                ((ushortT*)&qhi[db])[e] = hi;
                ((ushortT*)&qlo[db])[e] = f2bf(fs - bf2f(hi));
            }
        }
    }

    const ushortT* Kg = Kb + (size_t)bh*SS*DHD;
    const ushortT* Vg = Vt + (size_t)bh*DHD*SS;

    float m_r[4], l_r[4];
    #pragma unroll
    for (int r = 0; r < 4; ++r) { m_r[r] = -1e30f; l_r[r] = 0.f; }
    f32x4 oacc[8] = {};

    for (int kt = 0; kt < SS/64; ++kt) {
        __syncthreads();
        #pragma unroll
        for (int p = 0; p < 4; ++p) {
            const int row = (tid >> 4) + 16*p;
            const int colb = (tid & 15)*8;
            bf16x8 u = *reinterpret_cast<const bf16x8*>(&Kg[(size_t)(kt*64 + row)*DHD + colb]);
            *reinterpret_cast<bf16x8*>(&Kl[row*KLP + colb]) = u;
        }
        #pragma unroll
        for (int p = 0; p < 4; ++p) {
            const int dr = (tid >> 3) + 32*p;
            const int sb = (tid & 7)*8;
            bf16x8 u = *reinterpret_cast<const bf16x8*>(&Vg[(size_t)dr*SS + kt*64 + sb]);
            *reinterpret_cast<bf16x8*>(&Vl[dr*VLP + sb]) = u;
        }
        __syncthreads();

        f32x4 s[4] = {};
        #pragma unroll
        for (int db = 0; db < 4; ++db) {
            bf16x8 kf[4];
            #pragma unroll
            for (int kb = 0; kb < 4; ++kb)
                kf[kb] = *reinterpret_cast<const bf16x8*>(&Kl[(kb*16 + c)*KLP + db*32 + g*8]);
            #pragma unroll
            for (int kb = 0; kb < 4; ++kb) {
                s[kb] = __builtin_amdgcn_mfma_f32_16x16x32_bf16(qhi[db], kf[kb], s[kb], 0, 0, 0);
                s[kb] = __builtin_amdgcn_mfma_f32_16x16x32_bf16(qlo[db], kf[kb], s[kb], 0, 0, 0);
            }
        }

        float tmax[4];
        #pragma unroll
        for (int r = 0; r < 4; ++r)
            tmax[r] = fmaxf(fmaxf(s[0][r], s[1][r]), fmaxf(s[2][r], s[3][r]));
        #pragma unroll
        for (int off = 1; off < 16; off <<= 1)
            #pragma unroll
            for (int r = 0; r < 4; ++r)
                tmax[r] = fmaxf(tmax[r], __shfl_xor(tmax[r], off));
        float mn[4], corr[4];
        #pragma unroll
        for (int r = 0; r < 4; ++r) {
            mn[r] = fmaxf(m_r[r], tmax[r]);
            corr[r] = __expf(m_r[r] - mn[r]);
            m_r[r] = mn[r];
        }
        float tsum[4] = {0.f, 0.f, 0.f, 0.f};
        #pragma unroll
        for (int kb = 0; kb < 4; ++kb)
            #pragma unroll
            for (int r = 0; r < 4; ++r) {
                const float p = __expf(s[kb][r] - mn[r]);
                s[kb][r] = p;
                tsum[r] += p;
            }
        #pragma unroll
        for (int off = 1; off < 16; off <<= 1)
            #pragma unroll
            for (int r = 0; r < 4; ++r)
                tsum[r] += __shfl_xor(tsum[r], off);
        #pragma unroll
        for (int r = 0; r < 4; ++r) l_r[r] = l_r[r]*corr[r] + tsum[r];
        #pragma unroll
        for (int df = 0; df < 8; ++df)
            #pragma unroll
            for (int r = 0; r < 4; ++r)
                oacc[df][r] *= corr[r];

        #pragma unroll
        for (int kb = 0; kb < 4; ++kb)
            #pragma unroll
            for (int r = 0; r < 4; ++r)
                Pw[(g*4 + r)*PLP + kb*16 + c] = f2bf(s[kb][r]);

        #pragma unroll
        for (int kk = 0; kk < 2; ++kk) {
            bf16x8 pa = *reinterpret_cast<const bf16x8*>(&Pw[c*PLP + kk*32 + g*8]);
            #pragma unroll
            for (int df = 0; df < 8; ++df) {
                bf16x8 vb = *reinterpret_cast<const bf16x8*>(&Vl[(df*16 + c)*VLP + kk*32 + g*8]);
                oacc[df] = __builtin_amdgcn_mfma_f32_16x16x32_bf16(pa, vb, oacc[df], 0, 0, 0);
            }
        }
    }

    #pragma unroll
    for (int r = 0; r < 4; ++r) {
        const float inv = 1.0f / l_r[r];
        ushortT* orow = o16 + (size_t)(b*SS + q0 + g*4 + r)*D + h*DHD + c;
        #pragma unroll
        for (int df = 0; df < 8; ++df)
            orow[df*16] = f2bf(oacc[df][r] * inv);
    }
}

// =====================================================================
// add_ln_r: xout = LN(xin + sum_s P[s] + dbias) * s + b  (f32 + bf16 out)
// GATE: also computes gate softmax top-2.
// =====================================================================
template<int SK, int GATE>
__global__ __launch_bounds__(256)
void add_ln_r(const float* __restrict__ xin, const float* __restrict__ P,
              const float* __restrict__ dbias,
              const float* __restrict__ gs, const float* __restrict__ gb,
              float* __restrict__ x32, ushortT* __restrict__ x16,
              const float* __restrict__ Wg, const float* __restrict__ bg,
              float* __restrict__ gv, int* __restrict__ gi)
{
    const int row = blockIdx.x, tid = threadIdx.x;
    const size_t off = (size_t)row*D + tid*4;
    float4 a = *reinterpret_cast<const float4*>(xin + off);
    float d0, d1, d2, d3;
    {
        float4 bvd = *reinterpret_cast<const float4*>(dbias + tid*4);
        d0 = bvd.x; d1 = bvd.y; d2 = bvd.z; d3 = bvd.w;
    }
    #pragma unroll
    for (int s = 0; s < SK; ++s) {
        float4 pv = *reinterpret_cast<const float4*>(P + (size_t)s*TT*D + off);
        d0 += pv.x; d1 += pv.y; d2 += pv.z; d3 += pv.w;
    }
    float v0=a.x+d0, v1=a.y+d1, v2=a.z+d2, v3=a.w+d3;
    __shared__ float red[2][4];
    float s = v0+v1+v2+v3;
    #pragma unroll
    for (int o = 32; o; o >>= 1) s += __shfl_xor(s, o, 64);
    if ((tid & 63) == 0) red[0][tid>>6] = s;
    __syncthreads();
    const float mean = (red[0][0]+red[0][1]+red[0][2]+red[0][3]) * (1.0f/D);
    v0-=mean; v1-=mean; v2-=mean; v3-=mean;
    float qv = v0*v0+v1*v1+v2*v2+v3*v3;
    #pragma unroll
    for (int o = 32; o; o >>= 1) qv += __shfl_xor(qv, o, 64);
    if ((tid & 63) == 0) red[1][tid>>6] = qv;
    __syncthreads();
    const float var = (red[1][0]+red[1][1]+red[1][2]+red[1][3]) * (1.0f/D);
    const float rstd = rsqrtf(var + EPSV);
    float4 sv = *reinterpret_cast<const float4*>(gs + tid*4);
    float4 bv = *reinterpret_cast<const float4*>(gb + tid*4);
    float ov[4];
    ov[0] = v0*rstd*sv.x + bv.x;
    ov[1] = v1*rstd*sv.y + bv.y;
    ov[2] = v2*rstd*sv.z + bv.z;
    ov[3] = v3*rstd*sv.w + bv.w;
    float4 o4; o4.x=ov[0]; o4.y=ov[1]; o4.z=ov[2]; o4.w=ov[3];
    *reinterpret_cast<float4*>(x32 + off) = o4;
    ushort4 h4; h4.x=f2bf(ov[0]); h4.y=f2bf(ov[1]); h4.z=f2bf(ov[2]); h4.w=f2bf(ov[3]);
    *reinterpret_cast<ushort4*>(x16 + off) = h4;

    if constexpr (GATE) {
        float p[4] = {0.f, 0.f, 0.f, 0.f};
        #pragma unroll
        for (int e = 0; e < 4; ++e) {
            const float* wr = Wg + (size_t)e*D + tid*4;
            p[e] = ov[0]*wr[0] + ov[1]*wr[1] + ov[2]*wr[2] + ov[3]*wr[3];
        }
        #pragma unroll
        for (int o = 32; o; o >>= 1) {
            p[0] += __shfl_xor(p[0], o, 64); p[1] += __shfl_xor(p[1], o, 64);
            p[2] += __shfl_xor(p[2], o, 64); p[3] += __shfl_xor(p[3], o, 64);
        }
        __shared__ float gred[4][4];
        if ((tid & 63) == 0) {
            const int w = tid>>6;
            gred[w][0]=p[0]; gred[w][1]=p[1]; gred[w][2]=p[2]; gred[w][3]=p[3];
        }
        __syncthreads();
        if (tid == 0) {
            float g[4];
            #pragma unroll
            for (int e = 0; e < 4; ++e) g[e] = gred[0][e]+gred[1][e]+gred[2][e]+gred[3][e] + bg[e];
            const float mx = fmaxf(fmaxf(g[0],g[1]), fmaxf(g[2],g[3]));
            float ssum = 0.f;
            #pragma unroll
            for (int e = 0; e < 4; ++e) { g[e] = __expf(g[e]-mx); ssum += g[e]; }
            const float inv = 1.0f/ssum;
            #pragma unroll
            for (int e = 0; e < 4; ++e) g[e] *= inv;
            int i0 = 0;
            for (int e = 1; e < 4; ++e) if (g[e] > g[i0]) i0 = e;
            int i1 = (i0 == 0) ? 1 : 0;
            for (int e = 0; e < 4; ++e) if (e != i0 && g[e] > g[i1]) i1 = e;
            gv[row*2]   = g[i0]; gv[row*2+1] = g[i1];
            gi[row*2]   = i0;    gi[row*2+1] = i1;
        }
    }
}

// =====================================================================
__global__ __launch_bounds__(256)
void moe_combine(float* __restrict__ x, ushortT* __restrict__ x16,
                 const float* __restrict__ eo,
                 const float* __restrict__ gv, const int* __restrict__ gi)
{
    const size_t i = (size_t)blockIdx.x*256 + threadIdx.x;
    const int t = (int)(i >> 10);
    const float w0 = gv[t*2]*SPARS, w1 = gv[t*2+1]*SPARS;
    const size_t TD = (size_t)TT*D;
    const float e0 = eo[(size_t)gi[t*2]*TD + i];
    const float e1 = eo[(size_t)gi[t*2+1]*TD + i];
    const float r = x[i]*(1.0f-SPARS) + w0*e0 + w1*e1;
    x[i] = r;
    x16[i] = f2bf(r);
}

__global__ __launch_bounds__(256)
void addpos(const float* __restrict__ xin, const float* __restrict__ pos,
            float* __restrict__ xo, ushortT* __restrict__ x16)
{
    const size_t i = (size_t)blockIdx.x*256 + threadIdx.x;
    const float r = xin[i] + pos[i & ((size_t)SS*D - 1)];
    xo[i] = r;
    x16[i] = f2bf(r);
}

__global__ __launch_bounds__(64)
void final_kernel(const float* __restrict__ x, const float* __restrict__ Wf,
                  const float* __restrict__ bf, float* __restrict__ out)
{
    const int b = blockIdx.x / NCLS, n = blockIdx.x % NCLS;
    const float* xr = x + ((size_t)b*SS + SS-1)*D;
    const int tid = threadIdx.x;
    float s = 0.f;
    for (int d = tid; d < D; d += 64) s += xr[d]*Wf[(size_t)n*D + d];
    #pragma unroll
    for (int o = 32; o; o >>= 1) s += __shfl_xor(s, o, 64);
    if (tid == 0) out[b*NCLS + n] = s + bf[n];
}

// =====================================================================
extern "C" void kernel_launch(void* const* d_in, const int* in_sizes, int n_in,
                              void* d_out, int out_size, void* d_ws, size_t ws_size,
                              hipStream_t stream)
{
    const float* x_in = (const float*)d_in[0];
    const float* pos  = (const float*)d_in[1];
    const float* Wqkv = (const float*)d_in[2];
    const float* bqkv = (const float*)d_in[3];
    const float* Wo   = (const float*)d_in[4];
    const float* bo   = (const float*)d_in[5];
    const float* ln1s = (const float*)d_in[6];
    const float* ln1b = (const float*)d_in[7];
    const float* W1   = (const float*)d_in[8];
    const float* b1   = (const float*)d_in[9];
    const float* W2   = (const float*)d_in[10];
    const float* b2   = (const float*)d_in[11];
    const float* ln2s = (const float*)d_in[12];
    const float* ln2b = (const float*)d_in[13];
    const float* Wg   = (const float*)d_in[14];
    const float* bg   = (const float*)d_in[15];
    const float* We   = (const float*)d_in[16];
    const float* be   = (const float*)d_in[17];
    const float* Wf   = (const float*)d_in[18];
    const float* bf   = (const float*)d_in[19];
    float* out = (float*)d_out;

    // ---- weight element counts ----
    const long nWqkv = (long)NL*3*D*D;
    const long nWo   = (long)NL*D*D;
    const long nW1   = (long)NL*FF*D;
    const long nW2   = (long)NL*D*FF;
    const long nWe   = (long)NE*D*D;

    // ---- workspace layout ----
    float* ws     = (float*)d_ws;
    float*   xbuf  = ws;                                   // TT*D fp32      (8 MB)
    ushortT* xb16  = (ushortT*)(xbuf + (size_t)TT*D);      // TT*D bf16      (4 MB)
    ushortT* ob16  = xb16 + (size_t)TT*D;                  // TT*D bf16      (4 MB)
    float*   scratch = (float*)(ob16 + (size_t)TT*D);      // 4*TT*D floats  (32 MB)
    ushortT* hb16 = (ushortT*)(scratch + (size_t)TT*D*4);  // TT*FF bf16     (8 MB)
    float*   gv    = (float*)(hb16 + (size_t)TT*FF);       // TT*2
    int*     gi    = (int*)(gv + (size_t)TT*2);            // TT*2
    ushortT* wq16  = (ushortT*)(gi + (size_t)TT*2);        // bf16 weights (~200 MB)
    ushortT* wo16  = wq16 + nWqkv;
    ushortT* w116  = wo16 + nWo;
    ushortT* w216  = w116 + nW1;
    ushortT* we16  = w216 + nW2;
    // aliases inside scratch (time-disjoint):
    float*   Qbuf = scratch;                               // TT*D fp32 (8 MB)
    ushortT* Kb   = (ushortT*)(Qbuf + (size_t)TT*D);       // 4 MB  [bh][s][d]
    ushortT* Vb   = Kb + (size_t)TT*D;                     // 4 MB  [tok][D]
    ushortT* Vt   = Vb + (size_t)TT*D;                     // 4 MB  [bh][d][s]
    float*   parts  = scratch;                             // 4 x TT*D fp32 (32 MB)
    float*   ebuf   = scratch;                             // 4 x TT*D fp32 (32 MB)

    const dim3 blk(256);
    // one-time (per call) fp32 -> bf16 weight conversion (RNE, bitwise-same
    // rounding as in-staging convert)
    wconv<<<dim3(2048), blk, 0, stream>>>(Wqkv, wq16, nWqkv);
    wconv<<<dim3(1024), blk, 0, stream>>>(Wo,   wo16, nWo);
    wconv<<<dim3(2048), blk, 0, stream>>>(W1,   w116, nW1);
    wconv<<<dim3(2048), blk, 0, stream>>>(W2,   w216, nW2);
    wconv<<<dim3(512),  blk, 0, stream>>>(We,   we16, nWe);

    addpos<<<dim3(TT*D/256), blk, 0, stream>>>(x_in, pos, xbuf, xb16);

    for (int l = 0; l < NL; ++l) {
        // qkv GEMM, fused split epilogue: Q f32 / K bf16 [bh][s][d] / V bf16
        gemm_mfma<1,1,0,64,1><<<dim3(3*D/64, TT/128, 1), blk, 0, stream>>>(
            xb16, wq16 + (size_t)l*3*D*D, bqkv + (size_t)l*3*D, nullptr,
            TT, 3*D, D, D, 0, 0, 0, Qbuf, Kb, Vb);
        // V transpose (bf16 -> bf16, LDS tile, coalesced both sides)
        v_tr<<<dim3(SS/64, BB*NH), blk, 0, stream>>>(Vb, Vt);
        // flash attention -> ob16 (bf16)
        attn_mfma<<<dim3(SS/64, BB*NH), blk, 0, stream>>>(Qbuf, Kb, Vt, ob16);
        // o-proj: splitK=4 partials (512 blocks)
        gemm_mfma<1,4,0,128,0><<<dim3(D/128, TT/128, 4), blk, 0, stream>>>(
            ob16, wo16 + (size_t)l*D*D, bo, parts, TT, D, D, D/4, 0, 0, 0,
            nullptr, nullptr, nullptr);
        // x = LN(x + sum(parts) + bo)
        add_ln_r<4,0><<<dim3(TT), blk, 0, stream>>>(
            xbuf, parts, bo + (size_t)l*D, ln1s + (size_t)l*D, ln1b + (size_t)l*D,
            xbuf, xb16, nullptr, nullptr, nullptr, nullptr);
        // h = gelu(x @ W1^T + b1) -> bf16  (BN=64 -> 512 blocks)
        gemm_mfma<0,1,1,64,0><<<dim3(FF/64, TT/128, 1), blk, 0, stream>>>(
            xb16, w116 + (size_t)l*FF*D, b1 + (size_t)l*FF, hb16, TT, FF, D, D, 0, 0, 0,
            nullptr, nullptr, nullptr);
        // f2 = h @ W2^T: splitK=4 partials (512 blocks)
        gemm_mfma<1,4,0,128,0><<<dim3(D/128, TT/128, 4), blk, 0, stream>>>(
            hb16, w216 + (size_t)l*D*FF, b2, parts, TT, D, FF, FF/4, 0, 0, 0,
            nullptr, nullptr, nullptr);
        // x = LN(x + sum(parts) + b2) + fused gate top-2
        add_ln_r<4,1><<<dim3(TT), blk, 0, stream>>>(
            xbuf, parts, b2 + (size_t)l*D, ln2s + (size_t)l*D, ln2b + (size_t)l*D,
            xbuf, xb16, Wg, bg, gv, gi);
        // all 4 expert outputs in ONE launch (BN=64 -> 1024 blocks, dense)
        gemm_mfma<1,1,0,64,0><<<dim3(D/64, TT/128, NE), blk, 0, stream>>>(
            xb16, we16, be, ebuf, TT, D, D, D, (long)D*D, (long)D, (long)TT*D,
            nullptr, nullptr, nullptr);
        // x = x*0.5 + 0.5*(v0*E0 + v1*E1)
        moe_combine<<<dim3(TT*D/256), blk, 0, stream>>>(xbuf, xb16, ebuf, gv, gi);
    }
    final_kernel<<<dim3(BB*NCLS), dim3(64), 0, stream>>>(xbuf, Wf, bf, out);
}